// Round 1
// 808.001 us; speedup vs baseline: 1.0199x; 1.0199x over previous
//
#include <hip/hip_runtime.h>
#include <hip/hip_bf16.h>
#include <hip/hip_fp16.h>

// DLRM small: B=16384, VOCAB=2^20, EMBED=128
// bottom MLP 13->512->256->128 (relu), interaction (27x27 triu incl diag),
// top MLP 506->1024->1024->512->256->1 (relu except last).
//
// fp16 MFMA (16x16x32), fp32 acc.
// R2: XCD-aware chunk swizzle, final 256->1 layer fused into T3 epilogue.
// R3: top-MLP GEMMs T0/T1/T2 ported to 256x256/BK=64 8-wave 8-phase schedule
//     (learn_hip m201 template): XOR chunk swizzle (conflict-free ds_read_b128
//     via inverse-swizzled global source + linear global_load_lds dest),
//     double-buffered LDS (128 KiB), prefetch next K-tile during phases 1-2,
//     per-group vmcnt(0)+raw s_barrier (no __syncthreads drain in loop),
//     s_setprio around MFMA clusters. Grids: 256/256/128 wgs = exact fill.

#define BROWS 16384
#define VOCAB_MASK 1048575

typedef __attribute__((ext_vector_type(8))) _Float16 half8;
typedef __attribute__((ext_vector_type(4))) float f32x4;

__device__ __forceinline__ void gld16(const void* g, void* l) {
  __builtin_amdgcn_global_load_lds(
      (const __attribute__((address_space(1))) void*)g,
      (__attribute__((address_space(3))) void*)l, 16, 0, 0);
}

__device__ __forceinline__ f32x4 mfma_f16(half8 a, half8 b, f32x4 c) {
  return __builtin_amdgcn_mfma_f32_16x16x32_f16(a, b, c, 0, 0, 0);
}

// ---------------------------------------------------------------------------
// Fused init: blockIdx.z 0..6 = weight transposes fp32[K][N] -> fp16[N][Kp],
// z=7 = build dense fp16 [B][32] from x fp32 [B][39].
__global__ __launch_bounds__(256) void init_fused(
    const float* __restrict__ x, _Float16* __restrict__ dense16,
    const float* s0, const float* s1, const float* s2, const float* s3,
    const float* s4, const float* s5, const float* s6,
    _Float16* d0, _Float16* d1, _Float16* d2, _Float16* d3,
    _Float16* d4, _Float16* d5, _Float16* d6) {
  __shared__ float tile[32][33];
  int z = blockIdx.z;
  int tx = threadIdx.x & 31, ty = threadIdx.x >> 5;  // 32 x 8
  if (z < 7) {
    const float* srcs[7] = {s0, s1, s2, s3, s4, s5, s6};
    _Float16* dsts[7] = {d0, d1, d2, d3, d4, d5, d6};
    const int Ks[7]  = {13, 512, 256, 506, 1024, 1024, 512};
    const int Ns[7]  = {512, 256, 128, 1024, 1024, 512, 256};
    const int Kps[7] = {32, 512, 256, 512, 1024, 1024, 512};
    int K = Ks[z], N = Ns[z], Kp = Kps[z];
    int kb = blockIdx.y * 32, nb = blockIdx.x * 32;
    if (kb >= Kp || nb >= N) return;
    const float* src = srcs[z];
    _Float16* dst = dsts[z];
    #pragma unroll
    for (int i = 0; i < 32; i += 8) {
      int k = kb + ty + i, n = nb + tx;
      tile[ty + i][tx] = (k < K && n < N) ? src[(size_t)k * N + n] : 0.f;
    }
    __syncthreads();
    #pragma unroll
    for (int i = 0; i < 32; i += 8) {
      int n = nb + ty + i, k = kb + tx;
      if (n < N && k < Kp) dst[(size_t)n * Kp + k] = (_Float16)tile[tx][ty + i];
    }
  } else {
    int id = blockIdx.y * 32 + blockIdx.x;
    int base = id * 512 + threadIdx.x * 2;
    #pragma unroll
    for (int j = 0; j < 2; j++) {
      int i = base + j;
      int b = i >> 5, c = i & 31;
      dense16[i] = (c < 13) ? (_Float16)x[(size_t)b * 39 + c] : (_Float16)0.f;
    }
  }
}

// ---------------------------------------------------------------------------
// GEMM (small layers): C = act(A[M][K] * Bt[N][K]^T + bias), fp16, fp32 acc.
// 128x128 tile, BK=32, 4 waves. Used for bottom MLP + fused last layer.
template <int RELU, int FUSE>
__global__ __launch_bounds__(256, 3) void gemm_bt(
    const _Float16* __restrict__ A, const _Float16* __restrict__ Bt,
    const float* __restrict__ bias, _Float16* __restrict__ C,
    int M, int N, int K, int GY,
    const float* __restrict__ w4, const float* __restrict__ b4,
    float* __restrict__ out) {
  __shared__ __align__(16) char smem[128 * 136 * 2];
  _Float16* As = (_Float16*)smem;
  _Float16* Bs = As + 128 * 32;
  _Float16* Cs = (_Float16*)smem;
  constexpr int CS = 136;

  int id = blockIdx.x;
  int cs = GY * 8;
  int c = id / cs, r = id - c * cs;
  int m0 = (c * 8 + (r & 7)) * 128;
  int n0 = (r >> 3) * 128;

  int tid = threadIdx.x, lane = tid & 63;
  int wv = tid >> 6;
  int wm = (wv & 1) * 64, wn = (wv >> 1) * 64;
  int lm = lane & 15, q = lane >> 4;

  f32x4 zero = {0.f, 0.f, 0.f, 0.f};
  f32x4 acc[4][4];
  #pragma unroll
  for (int i = 0; i < 4; i++)
    #pragma unroll
    for (int j = 0; j < 4; j++) acc[i][j] = zero;

  int c0 = tid, c1 = tid + 256;  // 16B chunks: row=c>>2, off=(c&3)*8
  int r0 = c0 >> 2, o0 = (c0 & 3) * 8;
  int r1 = c1 >> 2, o1 = (c1 & 3) * 8;

  for (int kk = 0; kk < K; kk += 32) {
    __syncthreads();
    gld16(A + (size_t)(m0 + r0) * K + kk + o0, &As[c0 * 8]);
    gld16(A + (size_t)(m0 + r1) * K + kk + o1, &As[c1 * 8]);
    gld16(Bt + (size_t)(n0 + r0) * K + kk + o0, &Bs[c0 * 8]);
    gld16(Bt + (size_t)(n0 + r1) * K + kk + o1, &Bs[c1 * 8]);
    __syncthreads();

    half8 af[4], bf[4];
    #pragma unroll
    for (int i = 0; i < 4; i++)
      af[i] = *(const half8*)&As[(wm + i * 16 + lm) * 32 + q * 8];
    #pragma unroll
    for (int i = 0; i < 4; i++)
      bf[i] = *(const half8*)&Bs[(wn + i * 16 + lm) * 32 + q * 8];
    #pragma unroll
    for (int mi = 0; mi < 4; mi++)
      #pragma unroll
      for (int ni = 0; ni < 4; ni++)
        acc[mi][ni] = mfma_f16(af[mi], bf[ni], acc[mi][ni]);
  }

  if (!FUSE) {
    __syncthreads();
    #pragma unroll
    for (int ni = 0; ni < 4; ni++) {
      int col_l = wn + ni * 16 + lm;
      float bv = bias[n0 + col_l];
      #pragma unroll
      for (int mi = 0; mi < 4; mi++)
        #pragma unroll
        for (int rr = 0; rr < 4; rr++) {
          int row_l = wm + mi * 16 + q * 4 + rr;
          float v = acc[mi][ni][rr] + bv;
          if (RELU) v = v > 0.f ? v : 0.f;
          Cs[row_l * CS + col_l] = (_Float16)v;
        }
    }
    __syncthreads();
    int row = tid >> 1, hoff = (tid & 1) * 64;
    const f32x4* src = (const f32x4*)&Cs[row * CS + hoff];
    f32x4* dst = (f32x4*)&C[(size_t)(m0 + row) * N + n0 + hoff];
    #pragma unroll
    for (int j = 0; j < 8; j++) dst[j] = src[j];
  } else {
    float part[4][4];
    #pragma unroll
    for (int mi = 0; mi < 4; mi++)
      #pragma unroll
      for (int rr = 0; rr < 4; rr++) part[mi][rr] = 0.f;
    #pragma unroll
    for (int ni = 0; ni < 4; ni++) {
      int col = n0 + wn + ni * 16 + lm;
      float bv = bias[col], wv4 = w4[col];
      #pragma unroll
      for (int mi = 0; mi < 4; mi++)
        #pragma unroll
        for (int rr = 0; rr < 4; rr++) {
          float v = acc[mi][ni][rr] + bv;
          v = v > 0.f ? v : 0.f;
          part[mi][rr] += v * wv4;
        }
    }
    #pragma unroll
    for (int mi = 0; mi < 4; mi++)
      #pragma unroll
      for (int rr = 0; rr < 4; rr++) {
        float v = part[mi][rr];
        v += __shfl_xor(v, 1);
        v += __shfl_xor(v, 2);
        v += __shfl_xor(v, 4);
        v += __shfl_xor(v, 8);
        part[mi][rr] = v;
      }
    if (lm == 0) {
      float bout = (n0 == 0 && wn == 0) ? b4[0] : 0.f;
      #pragma unroll
      for (int mi = 0; mi < 4; mi++)
        #pragma unroll
        for (int rr = 0; rr < 4; rr++)
          atomicAdd(&out[m0 + wm + mi * 16 + q * 4 + rr],
                    part[mi][rr] + bout);
    }
  }
}

// ---------------------------------------------------------------------------
// GEMM (big top-MLP layers): 256x256 tile, BK=64, 512 threads (8 waves 2x4),
// 8-phase schedule, double-buffered 128 KiB LDS, XOR chunk swizzle.
// Grid: (M/256)*(N/256) 1-D, XCD-aware: id%8 = A-stripe -> XCD.
// C/D layout per 16x16 frag: col=lane&15, row=(lane>>4)*4+reg.
#define BAR256()                         \
  do {                                   \
    __builtin_amdgcn_s_barrier();        \
    __builtin_amdgcn_sched_barrier(0);   \
  } while (0)

#define STG(p0, p1, arr, sh, kk)                         \
  do {                                                   \
    gld16((p0) + (kk), &(arr)[(sh) * 8192 + ldst0]);     \
    gld16((p1) + (kk), &(arr)[(sh) * 8192 + ldst1]);     \
  } while (0)

template <int RELU>
__global__ __launch_bounds__(512, 2) void gemm256(
    const _Float16* __restrict__ A, const _Float16* __restrict__ Bt,
    const float* __restrict__ bias, _Float16* __restrict__ C,
    int N, int K) {
  // As/Bs: [slot(2)][half(2)][128 rows][64 k] fp16  -> 64 KiB each
  __shared__ __align__(16) _Float16 smem[65536];  // 128 KiB
  _Float16* As = smem;
  _Float16* Bs = smem + 32768;

  const int id = blockIdx.x;
  const int mb = (id & 7) * 8 + ((id >> 3) & 7);  // id%8 -> XCD owns A-stripe
  const int nb = id >> 6;

  const int tid = threadIdx.x;
  const int lane = tid & 63, wv = tid >> 6;
  const int lm = lane & 15, q = lane >> 4;
  const int wm = wv >> 2, wn = wv & 3;  // wave = 128-row half x 64-col quarter

  // ---- staging geometry: thread t covers LDS row sr(+64), chunk sc (16B).
  // LDS[r][c] holds global chunk c^(r&7)  (involution; read applies same XOR)
  const int sr = tid >> 3, sc = tid & 7;
  const int cc = sc ^ (sr & 7);
  const size_t K_ = (size_t)K;
  const _Float16* pA00 = A + ((size_t)(mb * 256) + sr) * K_ + cc * 8;
  const _Float16* pA01 = A + ((size_t)(mb * 256) + 64 + sr) * K_ + cc * 8;
  const _Float16* pA10 = pA00 + (size_t)128 * K_;
  const _Float16* pA11 = pA01 + (size_t)128 * K_;
  const _Float16* pB00 = Bt + ((size_t)(nb * 256) + sr) * K_ + cc * 8;
  const _Float16* pB01 = Bt + ((size_t)(nb * 256) + 64 + sr) * K_ + cc * 8;
  const _Float16* pB10 = pB00 + (size_t)128 * K_;
  const _Float16* pB11 = pB01 + (size_t)128 * K_;
  const int ldst0 = tid * 8;         // rows 0..63 of half-tile
  const int ldst1 = 4096 + tid * 8;  // rows 64..127

  // ---- fragment read offsets (elements, within a [128][64] half):
  // row = frag*16+lm, logical chunk = ks*4+q, physical = logical^(lm&7)
  const int co0 = ((q) ^ (lm & 7)) * 8;
  const int co1 = ((4 + q) ^ (lm & 7)) * 8;
  const int aro = wm * 8192 + lm * 64;                           // + mi*1024
  const int bro = (wn >> 1) * 8192 + ((wn & 1) * 64 + lm) * 64;  // + nj*1024

  f32x4 acc[8][4];
  #pragma unroll
  for (int i = 0; i < 8; ++i)
    #pragma unroll
    for (int j = 0; j < 4; ++j) acc[i][j] = (f32x4){0.f, 0.f, 0.f, 0.f};

  // ---- prologue: stage K-tile 0 into slot 0, full drain once
  STG(pA00, pA01, As, 0, 0);
  STG(pA10, pA11, As, 1, 0);
  STG(pB00, pB01, Bs, 0, 0);
  STG(pB10, pB11, Bs, 1, 0);
  asm volatile("s_waitcnt vmcnt(0)" ::: "memory");
  BAR256();

  const int NT = K >> 6;
  for (int kt = 0; kt < NT; ++kt) {
    const int s = kt & 1;
    const int sb = s * 16384;
    const int snb = (s ^ 1) * 2;
    const int kkn = (kt + 1) * 64;
    const bool pf = (kt + 1) < NT;
    half8 af[4][2], bf[2][2];

    // ---- P1: Q(m0-3, n0-1); prefetch next A-halves
    #pragma unroll
    for (int j = 0; j < 4; ++j) {
      af[j][0] = *(const half8*)&As[sb + aro + j * 1024 + co0];
      af[j][1] = *(const half8*)&As[sb + aro + j * 1024 + co1];
    }
    #pragma unroll
    for (int n = 0; n < 2; ++n) {
      bf[n][0] = *(const half8*)&Bs[sb + bro + n * 1024 + co0];
      bf[n][1] = *(const half8*)&Bs[sb + bro + n * 1024 + co1];
    }
    if (pf) { STG(pA00, pA01, As, snb, kkn); STG(pA10, pA11, As, snb + 1, kkn); }
    BAR256();
    __builtin_amdgcn_s_setprio(1);
    #pragma unroll
    for (int j = 0; j < 4; ++j)
      #pragma unroll
      for (int n = 0; n < 2; ++n) {
        acc[j][n] = mfma_f16(af[j][0], bf[n][0], acc[j][n]);
        acc[j][n] = mfma_f16(af[j][1], bf[n][1], acc[j][n]);
      }
    __builtin_amdgcn_s_setprio(0);
    BAR256();

    // ---- P2: Q(m0-3, n2-3); reuse af; prefetch next B-halves
    #pragma unroll
    for (int n = 0; n < 2; ++n) {
      bf[n][0] = *(const half8*)&Bs[sb + bro + (2 + n) * 1024 + co0];
      bf[n][1] = *(const half8*)&Bs[sb + bro + (2 + n) * 1024 + co1];
    }
    if (pf) { STG(pB00, pB01, Bs, snb, kkn); STG(pB10, pB11, Bs, snb + 1, kkn); }
    BAR256();
    __builtin_amdgcn_s_setprio(1);
    #pragma unroll
    for (int j = 0; j < 4; ++j)
      #pragma unroll
      for (int n = 0; n < 2; ++n) {
        acc[j][2 + n] = mfma_f16(af[j][0], bf[n][0], acc[j][2 + n]);
        acc[j][2 + n] = mfma_f16(af[j][1], bf[n][1], acc[j][2 + n]);
      }
    __builtin_amdgcn_s_setprio(0);
    BAR256();

    // ---- P3: Q(m4-7, n2-3); reuse bf
    #pragma unroll
    for (int j = 0; j < 4; ++j) {
      af[j][0] = *(const half8*)&As[sb + aro + (4 + j) * 1024 + co0];
      af[j][1] = *(const half8*)&As[sb + aro + (4 + j) * 1024 + co1];
    }
    BAR256();
    __builtin_amdgcn_s_setprio(1);
    #pragma unroll
    for (int j = 0; j < 4; ++j)
      #pragma unroll
      for (int n = 0; n < 2; ++n) {
        acc[4 + j][2 + n] = mfma_f16(af[j][0], bf[n][0], acc[4 + j][2 + n]);
        acc[4 + j][2 + n] = mfma_f16(af[j][1], bf[n][1], acc[4 + j][2 + n]);
      }
    __builtin_amdgcn_s_setprio(0);
    BAR256();

    // ---- P4: Q(m4-7, n0-1); re-read bf n0-1; group-end wait (per-wave
    // vmcnt(0) is ~free: stages issued 2-3 phases earlier), then barrier
    // makes all waves' async LDS writes visible before next group reads.
    #pragma unroll
    for (int n = 0; n < 2; ++n) {
      bf[n][0] = *(const half8*)&Bs[sb + bro + n * 1024 + co0];
      bf[n][1] = *(const half8*)&Bs[sb + bro + n * 1024 + co1];
    }
    BAR256();
    __builtin_amdgcn_s_setprio(1);
    #pragma unroll
    for (int j = 0; j < 4; ++j)
      #pragma unroll
      for (int n = 0; n < 2; ++n) {
        acc[4 + j][n] = mfma_f16(af[j][0], bf[n][0], acc[4 + j][n]);
        acc[4 + j][n] = mfma_f16(af[j][1], bf[n][1], acc[4 + j][n]);
      }
    __builtin_amdgcn_s_setprio(0);
    asm volatile("s_waitcnt vmcnt(0)" ::: "memory");
    BAR256();
  }

  // ---- epilogue: bias+relu -> fp16, staged through LDS in 2 half-rounds
  constexpr int CS = 264;
  _Float16* Cs = smem;
  const float* bp = bias + nb * 256 + wn * 64 + lm;
  const int crow = tid >> 2, cq = tid & 3;
  #pragma unroll
  for (int h = 0; h < 2; ++h) {
    if (wm == h) {
      #pragma unroll
      for (int ni = 0; ni < 4; ++ni) {
        float bv = bp[ni * 16];
        #pragma unroll
        for (int mi = 0; mi < 8; ++mi)
          #pragma unroll
          for (int rr = 0; rr < 4; ++rr) {
            float v = acc[mi][ni][rr] + bv;
            if (RELU) v = v > 0.f ? v : 0.f;
            Cs[(mi * 16 + q * 4 + rr) * CS + wn * 64 + ni * 16 + lm] =
                (_Float16)v;
          }
      }
    }
    __syncthreads();
    {
      const size_t rbase = (size_t)(mb * 256 + h * 128 + crow) * N + nb * 256;
      #pragma unroll
      for (int j = 0; j < 8; ++j) {
        int c16 = j * 4 + cq;
        *(f32x4*)&C[rbase + c16 * 8] = *(const f32x4*)&Cs[crow * CS + c16 * 8];
      }
    }
    __syncthreads();
  }
}

// ---------------------------------------------------------------------------
// Interaction: per sample, X = [h; emb_rows; zeros] (32x128 fp16), S = X*X^T,
// feat = [h | triu(S[0:27][0:27]) | 0 pad to 512]. One wave per sample.
__global__ __launch_bounds__(256) void interact_kernel(
    const float* __restrict__ x, const float* __restrict__ emb,
    const _Float16* __restrict__ h, _Float16* __restrict__ feat) {
  constexpr int XS = 136;
  __shared__ __align__(16) _Float16 X[4][32 * XS];
  __shared__ __align__(16) _Float16 F[4][512];
  __shared__ int IDX[4][26];
  int tid = threadIdx.x, wv = tid >> 6, lane = tid & 63;
  size_t b = (size_t)blockIdx.x * 4 + wv;

  if (lane < 26) IDX[wv][lane] = ((int)x[b * 39 + 13 + lane]) & VOCAB_MASK;
  {
    const _Float16* hp = h + b * 128;
    *(unsigned*)&X[wv][lane * 2] = *(const unsigned*)&hp[lane * 2];
  }
  #pragma unroll
  for (int r = 27; r < 32; r++) {
    X[wv][r * XS + lane] = (_Float16)0.f;
    X[wv][r * XS + lane + 64] = (_Float16)0.f;
  }
  __syncthreads();

  #pragma unroll
  for (int it = 0; it < 13; it++) {
    int r = 1 + it * 2 + (lane >> 5);
    int c = (lane & 31) * 4;
    int idx = IDX[wv][r - 1];
    float4 v = *(const float4*)(emb + (size_t)idx * 128 + c);
    _Float16* d = &X[wv][r * XS + c];
    d[0] = (_Float16)v.x; d[1] = (_Float16)v.y;
    d[2] = (_Float16)v.z; d[3] = (_Float16)v.w;
  }
  __syncthreads();

  f32x4 zero = {0.f, 0.f, 0.f, 0.f};
  f32x4 acc[2][2] = {{zero, zero}, {zero, zero}};
  int lm = lane & 15, q = lane >> 4;
  #pragma unroll
  for (int ks = 0; ks < 4; ks++) {
    half8 f0 = *(const half8*)&X[wv][(lm) * XS + ks * 32 + q * 8];
    half8 f1 = *(const half8*)&X[wv][(16 + lm) * XS + ks * 32 + q * 8];
    acc[0][0] = mfma_f16(f0, f0, acc[0][0]);
    acc[0][1] = mfma_f16(f0, f1, acc[0][1]);
    acc[1][0] = mfma_f16(f1, f0, acc[1][0]);
    acc[1][1] = mfma_f16(f1, f1, acc[1][1]);
  }

  *(unsigned*)&F[wv][lane * 2] = *(const unsigned*)&X[wv][lane * 2];
  if (lane < 6) F[wv][506 + lane] = (_Float16)0.f;
  #pragma unroll
  for (int mt = 0; mt < 2; mt++)
    #pragma unroll
    for (int nt = 0; nt < 2; nt++)
      #pragma unroll
      for (int r = 0; r < 4; r++) {
        int i = mt * 16 + q * 4 + r;
        int j = nt * 16 + lm;
        if (i <= j && j < 27) {
          int off = 128 + i * 27 - i * (i - 1) / 2 + (j - i);
          F[wv][off] = (_Float16)acc[mt][nt][r];
        }
      }
  __syncthreads();

  *(float4*)(feat + b * 512 + lane * 8) = *(const float4*)&F[wv][lane * 8];
}

// ---------------------------------------------------------------------------
extern "C" void kernel_launch(void* const* d_in, const int* in_sizes, int n_in,
                              void* d_out, int out_size, void* d_ws, size_t ws_size,
                              hipStream_t stream) {
  const float* x   = (const float*)d_in[0];
  const float* emb = (const float*)d_in[1];
  const float* bw0 = (const float*)d_in[2];
  const float* bb0 = (const float*)d_in[3];
  const float* bw1 = (const float*)d_in[4];
  const float* bb1 = (const float*)d_in[5];
  const float* bw2 = (const float*)d_in[6];
  const float* bb2 = (const float*)d_in[7];
  const float* tw0 = (const float*)d_in[8];
  const float* tb0 = (const float*)d_in[9];
  const float* tw1 = (const float*)d_in[10];
  const float* tb1 = (const float*)d_in[11];
  const float* tw2 = (const float*)d_in[12];
  const float* tb2 = (const float*)d_in[13];
  const float* tw3 = (const float*)d_in[14];
  const float* tb3 = (const float*)d_in[15];
  const float* tw4 = (const float*)d_in[16];
  const float* tb4 = (const float*)d_in[17];
  float* out = (float*)d_out;

  char* ws = (char*)d_ws;
  _Float16* w0T = (_Float16*)ws;          // [512][32]
  _Float16* w1T = w0T + 512 * 32;         // [256][512]
  _Float16* w2T = w1T + 256 * 512;        // [128][256]
  _Float16* t0T = w2T + 128 * 256;        // [1024][512]
  _Float16* t1T = t0T + 1024 * 512;       // [1024][1024]
  _Float16* t2T = t1T + 1024 * 1024;      // [512][1024]
  _Float16* t3T = t2T + 512 * 1024;       // [256][512]

  char* P1 = ws + (size_t)(5u << 20);
  char* P2 = ws + (size_t)(37u << 20);
  _Float16* dense16 = (_Float16*)P1;  // [B][32]
  _Float16* a1 = (_Float16*)P2;       // [B][512]
  _Float16* a2 = (_Float16*)P1;       // [B][256]
  _Float16* hb = (_Float16*)P2;       // [B][128]
  _Float16* ft = (_Float16*)P1;       // [B][512]
  _Float16* t0 = (_Float16*)P2;       // [B][1024]
  _Float16* t1 = (_Float16*)P1;       // [B][1024]
  _Float16* t2 = (_Float16*)P2;       // [B][512]

  hipMemsetAsync(d_out, 0, (size_t)out_size * sizeof(float), stream);

  init_fused<<<dim3(32, 32, 8), 256, 0, stream>>>(
      x, dense16, bw0, bw1, bw2, tw0, tw1, tw2, tw3,
      w0T, w1T, w2T, t0T, t1T, t2T, t3T);

  gemm_bt<1, 0><<<128 * 4, 256, 0, stream>>>(dense16, w0T, bb0, a1,
      BROWS, 512, 32, 4, nullptr, nullptr, nullptr);
  gemm_bt<1, 0><<<128 * 2, 256, 0, stream>>>(a1, w1T, bb1, a2,
      BROWS, 256, 512, 2, nullptr, nullptr, nullptr);
  gemm_bt<1, 0><<<128 * 1, 256, 0, stream>>>(a2, w2T, bb2, hb,
      BROWS, 128, 256, 1, nullptr, nullptr, nullptr);

  interact_kernel<<<BROWS / 4, 256, 0, stream>>>(x, emb, hb, ft);

  // top MLP big layers: 256x256 8-phase kernel, exact-fill grids
  gemm256<1><<<256, 512, 0, stream>>>(ft, t0T, tb0, t0, 1024, 512);
  gemm256<1><<<256, 512, 0, stream>>>(t0, t1T, tb1, t1, 1024, 1024);
  gemm256<1><<<128, 512, 0, stream>>>(t1, t2T, tb2, t2, 512, 1024);

  gemm_bt<1, 1><<<128 * 2, 256, 0, stream>>>(t2, t3T, tb3, nullptr,
      BROWS, 256, 512, 2, tw4, tb4, out);
}

// Round 4
// 787.391 us; speedup vs baseline: 1.0466x; 1.0262x over previous
//
#include <hip/hip_runtime.h>
#include <hip/hip_bf16.h>
#include <hip/hip_fp16.h>

// DLRM small: B=16384, VOCAB=2^20, EMBED=128
// bottom MLP 13->512->256->128 (relu), interaction (27x27 triu incl diag),
// top MLP 506->1024->1024->512->256->1 (relu except last).
//
// fp16 MFMA (16x16x32), fp32 acc.
// R2: XCD-aware chunk swizzle, final 256->1 layer fused into T3 epilogue.
// R3: T0/T1/T2 on 256x256/BK=64 8-wave 8-phase schedule (m201 template).
// R4/R5: bottom-MLP fusion + gemm128 ring for T2 — two container failures.
// R6: BISECT. Keep bottom_fused (low-risk, conventional sync) + init z=7
//     out-zeroing; REVERT T2 to the R1-proven gemm256<<<128>>> path; drop
//     gemm128 (novel vmcnt-ring sync = prime hang suspect) entirely.
//     Pipeline: init, bottom, interact, T0, T1, T2(gemm256), T3 = 7 launches.

#define BROWS 16384
#define VOCAB_MASK 1048575

typedef __attribute__((ext_vector_type(8))) _Float16 half8;
typedef __attribute__((ext_vector_type(4))) float f32x4;

__device__ __forceinline__ void gld16(const void* g, void* l) {
  __builtin_amdgcn_global_load_lds(
      (const __attribute__((address_space(1))) void*)g,
      (__attribute__((address_space(3))) void*)l, 16, 0, 0);
}

__device__ __forceinline__ f32x4 mfma_f16(half8 a, half8 b, f32x4 c) {
  return __builtin_amdgcn_mfma_f32_16x16x32_f16(a, b, c, 0, 0, 0);
}

// XOR chunk swizzle within a row: c in halfs, 16B chunks, involution.
__device__ __forceinline__ int xsw(int r, int c) {
  return (((c >> 3) ^ (r & 7)) << 3) | (c & 7);
}

// ---------------------------------------------------------------------------
// Fused init: blockIdx.z 0..6 = weight transposes fp32[K][N] -> fp16[N][Kp],
// z=7 = zero the output vector (replaces hipMemsetAsync dispatch).
__global__ __launch_bounds__(256) void init_fused(
    float* __restrict__ out,
    const float* s0, const float* s1, const float* s2, const float* s3,
    const float* s4, const float* s5, const float* s6,
    _Float16* d0, _Float16* d1, _Float16* d2, _Float16* d3,
    _Float16* d4, _Float16* d5, _Float16* d6) {
  __shared__ float tile[32][33];
  int z = blockIdx.z;
  int tx = threadIdx.x & 31, ty = threadIdx.x >> 5;  // 32 x 8
  if (z < 7) {
    const float* srcs[7] = {s0, s1, s2, s3, s4, s5, s6};
    _Float16* dsts[7] = {d0, d1, d2, d3, d4, d5, d6};
    const int Ks[7]  = {13, 512, 256, 506, 1024, 1024, 512};
    const int Ns[7]  = {512, 256, 128, 1024, 1024, 512, 256};
    const int Kps[7] = {32, 512, 256, 512, 1024, 1024, 512};
    int K = Ks[z], N = Ns[z], Kp = Kps[z];
    int kb = blockIdx.y * 32, nb = blockIdx.x * 32;
    if (kb >= Kp || nb >= N) return;
    const float* src = srcs[z];
    _Float16* dst = dsts[z];
    #pragma unroll
    for (int i = 0; i < 32; i += 8) {
      int k = kb + ty + i, n = nb + tx;
      tile[ty + i][tx] = (k < K && n < N) ? src[(size_t)k * N + n] : 0.f;
    }
    __syncthreads();
    #pragma unroll
    for (int i = 0; i < 32; i += 8) {
      int n = nb + ty + i, k = kb + tx;
      if (n < N && k < Kp) dst[(size_t)n * Kp + k] = (_Float16)tile[tx][ty + i];
    }
  } else {
    // zero out[16384] with 16 blocks x 256 threads x float4
    if (blockIdx.y == 0 && blockIdx.x < 16) {
      int id = blockIdx.x * 256 + threadIdx.x;
      *(f32x4*)&out[id * 4] = (f32x4){0.f, 0.f, 0.f, 0.f};
    }
  }
}

// ---------------------------------------------------------------------------
// Fused bottom MLP: x[B][39] -> dense(13,pad32) -> 512 -> 256 -> 128 (relu).
// 256 blocks x 512 threads (8 waves), 64 rows/block. a1/a2 live in
// XOR-swizzled LDS; weights (w0T 32KB, w1T 256KB, w2T 64KB) stream from L2.
__global__ __launch_bounds__(512, 2) void bottom_fused(
    const float* __restrict__ x,
    const _Float16* __restrict__ w0T, const float* __restrict__ bb0,
    const _Float16* __restrict__ w1T, const float* __restrict__ bb1,
    const _Float16* __restrict__ w2T, const float* __restrict__ bb2,
    _Float16* __restrict__ hb) {
  constexpr int SD = 40;  // dense row stride (halfs); 80B = 5*16B aligned
  __shared__ __align__(16) _Float16 a1s[64 * 512];  // 64KB, swizzled
  __shared__ __align__(16) _Float16 a2s[64 * 256];  // 32KB, swizzled
  __shared__ __align__(16) _Float16 ds[64 * SD];    // 5KB

  const int tid = threadIdx.x, lane = tid & 63, wv = tid >> 6;
  const int lm = lane & 15, q = lane >> 4;
  const int row0 = blockIdx.x * 64;

  // dense: 64 x 32 fp16, cols >=13 zeroed (w0T rows >=13 are zero too)
  for (int i = tid; i < 64 * 32; i += 512) {
    int r = i >> 5, c = i & 31;
    ds[r * SD + c] =
        (c < 13) ? (_Float16)x[(size_t)(row0 + r) * 39 + c] : (_Float16)0.f;
  }
  __syncthreads();

  // GEMM1: [64x32] @ w0T[512][32]^T -> a1[64][512], relu. K=32 = 1 mfma.
  {
    f32x4 acc[4][4];
    #pragma unroll
    for (int m = 0; m < 4; ++m)
      #pragma unroll
      for (int n = 0; n < 4; ++n) acc[m][n] = (f32x4){0.f, 0.f, 0.f, 0.f};
    half8 af[4];
    #pragma unroll
    for (int m = 0; m < 4; ++m)
      af[m] = *(const half8*)&ds[(m * 16 + lm) * SD + q * 8];
    #pragma unroll
    for (int n = 0; n < 4; ++n) {
      half8 bf =
          *(const half8*)&w0T[(size_t)(wv * 64 + n * 16 + lm) * 32 + q * 8];
      #pragma unroll
      for (int m = 0; m < 4; ++m) acc[m][n] = mfma_f16(af[m], bf, acc[m][n]);
    }
    #pragma unroll
    for (int n = 0; n < 4; ++n) {
      int col = wv * 64 + n * 16 + lm;
      float bv = bb0[col];
      #pragma unroll
      for (int m = 0; m < 4; ++m)
        #pragma unroll
        for (int rr = 0; rr < 4; ++rr) {
          int r = m * 16 + q * 4 + rr;
          float v = acc[m][n][rr] + bv;
          v = v > 0.f ? v : 0.f;
          a1s[r * 512 + xsw(r, col)] = (_Float16)v;
        }
    }
  }
  __syncthreads();

  // GEMM2: a1[64][512] @ w1T[256][512]^T -> a2[64][256], relu.
  {
    f32x4 acc[4][2];
    #pragma unroll
    for (int m = 0; m < 4; ++m)
      #pragma unroll
      for (int n = 0; n < 2; ++n) acc[m][n] = (f32x4){0.f, 0.f, 0.f, 0.f};
    #pragma unroll
    for (int kk = 0; kk < 512; kk += 32) {
      half8 af[4], bf[2];
      #pragma unroll
      for (int m = 0; m < 4; ++m) {
        int r = m * 16 + lm;
        af[m] = *(const half8*)&a1s[r * 512 + xsw(r, kk + q * 8)];
      }
      #pragma unroll
      for (int n = 0; n < 2; ++n)
        bf[n] = *(const half8*)&w1T[(size_t)(wv * 32 + n * 16 + lm) * 512 +
                                    kk + q * 8];
      #pragma unroll
      for (int m = 0; m < 4; ++m)
        #pragma unroll
        for (int n = 0; n < 2; ++n)
          acc[m][n] = mfma_f16(af[m], bf[n], acc[m][n]);
    }
    #pragma unroll
    for (int n = 0; n < 2; ++n) {
      int col = wv * 32 + n * 16 + lm;
      float bv = bb1[col];
      #pragma unroll
      for (int m = 0; m < 4; ++m)
        #pragma unroll
        for (int rr = 0; rr < 4; ++rr) {
          int r = m * 16 + q * 4 + rr;
          float v = acc[m][n][rr] + bv;
          v = v > 0.f ? v : 0.f;
          a2s[r * 256 + xsw(r, col)] = (_Float16)v;
        }
    }
  }
  __syncthreads();

  // GEMM3: a2[64][256] @ w2T[128][256]^T -> hb[64][128], relu, to global.
  {
    f32x4 acc[4];
    #pragma unroll
    for (int m = 0; m < 4; ++m) acc[m] = (f32x4){0.f, 0.f, 0.f, 0.f};
    const int col = wv * 16 + lm;
    #pragma unroll
    for (int kk = 0; kk < 256; kk += 32) {
      half8 bf = *(const half8*)&w2T[(size_t)col * 256 + kk + q * 8];
      #pragma unroll
      for (int m = 0; m < 4; ++m) {
        int r = m * 16 + lm;
        half8 af = *(const half8*)&a2s[r * 256 + xsw(r, kk + q * 8)];
        acc[m] = mfma_f16(af, bf, acc[m]);
      }
    }
    float bv = bb2[col];
    #pragma unroll
    for (int m = 0; m < 4; ++m)
      #pragma unroll
      for (int rr = 0; rr < 4; ++rr) {
        float v = acc[m][rr] + bv;
        v = v > 0.f ? v : 0.f;
        hb[(size_t)(row0 + m * 16 + q * 4 + rr) * 128 + col] = (_Float16)v;
      }
  }
}

// ---------------------------------------------------------------------------
// GEMM (T3): C = act(A*Bt^T+bias) with fused last layer. 128x128, BK=32.
template <int RELU, int FUSE>
__global__ __launch_bounds__(256, 3) void gemm_bt(
    const _Float16* __restrict__ A, const _Float16* __restrict__ Bt,
    const float* __restrict__ bias, _Float16* __restrict__ C,
    int M, int N, int K, int GY,
    const float* __restrict__ w4, const float* __restrict__ b4,
    float* __restrict__ out) {
  __shared__ __align__(16) char smem[128 * 136 * 2];
  _Float16* As = (_Float16*)smem;
  _Float16* Bs = As + 128 * 32;
  _Float16* Cs = (_Float16*)smem;
  constexpr int CS = 136;

  int id = blockIdx.x;
  int cs = GY * 8;
  int c = id / cs, r = id - c * cs;
  int m0 = (c * 8 + (r & 7)) * 128;
  int n0 = (r >> 3) * 128;

  int tid = threadIdx.x, lane = tid & 63;
  int wv = tid >> 6;
  int wm = (wv & 1) * 64, wn = (wv >> 1) * 64;
  int lm = lane & 15, q = lane >> 4;

  f32x4 zero = {0.f, 0.f, 0.f, 0.f};
  f32x4 acc[4][4];
  #pragma unroll
  for (int i = 0; i < 4; i++)
    #pragma unroll
    for (int j = 0; j < 4; j++) acc[i][j] = zero;

  int c0 = tid, c1 = tid + 256;
  int r0 = c0 >> 2, o0 = (c0 & 3) * 8;
  int r1 = c1 >> 2, o1 = (c1 & 3) * 8;

  for (int kk = 0; kk < K; kk += 32) {
    __syncthreads();
    gld16(A + (size_t)(m0 + r0) * K + kk + o0, &As[c0 * 8]);
    gld16(A + (size_t)(m0 + r1) * K + kk + o1, &As[c1 * 8]);
    gld16(Bt + (size_t)(n0 + r0) * K + kk + o0, &Bs[c0 * 8]);
    gld16(Bt + (size_t)(n0 + r1) * K + kk + o1, &Bs[c1 * 8]);
    __syncthreads();

    half8 af[4], bf[4];
    #pragma unroll
    for (int i = 0; i < 4; i++)
      af[i] = *(const half8*)&As[(wm + i * 16 + lm) * 32 + q * 8];
    #pragma unroll
    for (int i = 0; i < 4; i++)
      bf[i] = *(const half8*)&Bs[(wn + i * 16 + lm) * 32 + q * 8];
    #pragma unroll
    for (int mi = 0; mi < 4; mi++)
      #pragma unroll
      for (int ni = 0; ni < 4; ni++)
        acc[mi][ni] = mfma_f16(af[mi], bf[ni], acc[mi][ni]);
  }

  if (!FUSE) {
    __syncthreads();
    #pragma unroll
    for (int ni = 0; ni < 4; ni++) {
      int col_l = wn + ni * 16 + lm;
      float bv = bias[n0 + col_l];
      #pragma unroll
      for (int mi = 0; mi < 4; mi++)
        #pragma unroll
        for (int rr = 0; rr < 4; rr++) {
          int row_l = wm + mi * 16 + q * 4 + rr;
          float v = acc[mi][ni][rr] + bv;
          if (RELU) v = v > 0.f ? v : 0.f;
          Cs[row_l * CS + col_l] = (_Float16)v;
        }
    }
    __syncthreads();
    int row = tid >> 1, hoff = (tid & 1) * 64;
    const f32x4* src = (const f32x4*)&Cs[row * CS + hoff];
    f32x4* dst = (f32x4*)&C[(size_t)(m0 + row) * N + n0 + hoff];
    #pragma unroll
    for (int j = 0; j < 8; j++) dst[j] = src[j];
  } else {
    float part[4][4];
    #pragma unroll
    for (int mi = 0; mi < 4; mi++)
      #pragma unroll
      for (int rr = 0; rr < 4; rr++) part[mi][rr] = 0.f;
    #pragma unroll
    for (int ni = 0; ni < 4; ni++) {
      int col = n0 + wn + ni * 16 + lm;
      float bv = bias[col], wv4 = w4[col];
      #pragma unroll
      for (int mi = 0; mi < 4; mi++)
        #pragma unroll
        for (int rr = 0; rr < 4; rr++) {
          float v = acc[mi][ni][rr] + bv;
          v = v > 0.f ? v : 0.f;
          part[mi][rr] += v * wv4;
        }
    }
    #pragma unroll
    for (int mi = 0; mi < 4; mi++)
      #pragma unroll
      for (int rr = 0; rr < 4; rr++) {
        float v = part[mi][rr];
        v += __shfl_xor(v, 1);
        v += __shfl_xor(v, 2);
        v += __shfl_xor(v, 4);
        v += __shfl_xor(v, 8);
        part[mi][rr] = v;
      }
    if (lm == 0) {
      float bout = (n0 == 0 && wn == 0) ? b4[0] : 0.f;
      #pragma unroll
      for (int mi = 0; mi < 4; mi++)
        #pragma unroll
        for (int rr = 0; rr < 4; rr++)
          atomicAdd(&out[m0 + wm + mi * 16 + q * 4 + rr],
                    part[mi][rr] + bout);
    }
  }
}

// ---------------------------------------------------------------------------
#define BAR256()                         \
  do {                                   \
    __builtin_amdgcn_s_barrier();        \
    __builtin_amdgcn_sched_barrier(0);   \
  } while (0)

#define STG(p0, p1, arr, sh, kk)                         \
  do {                                                   \
    gld16((p0) + (kk), &(arr)[(sh) * 8192 + ldst0]);     \
    gld16((p1) + (kk), &(arr)[(sh) * 8192 + ldst1]);     \
  } while (0)

// GEMM 256x256/BK=64, 8 waves, 8-phase, 2-slot LDS (128 KiB). T0/T1/T2.
template <int RELU>
__global__ __launch_bounds__(512, 2) void gemm256(
    const _Float16* __restrict__ A, const _Float16* __restrict__ Bt,
    const float* __restrict__ bias, _Float16* __restrict__ C,
    int N, int K) {
  __shared__ __align__(16) _Float16 smem[65536];  // 128 KiB
  _Float16* As = smem;
  _Float16* Bs = smem + 32768;

  const int id = blockIdx.x;
  const int mb = (id & 7) * 8 + ((id >> 3) & 7);
  const int nb = id >> 6;

  const int tid = threadIdx.x;
  const int lane = tid & 63, wv = tid >> 6;
  const int lm = lane & 15, q = lane >> 4;
  const int wm = wv >> 2, wn = wv & 3;

  const int sr = tid >> 3, sc = tid & 7;
  const int cc = sc ^ (sr & 7);
  const size_t K_ = (size_t)K;
  const _Float16* pA00 = A + ((size_t)(mb * 256) + sr) * K_ + cc * 8;
  const _Float16* pA01 = A + ((size_t)(mb * 256) + 64 + sr) * K_ + cc * 8;
  const _Float16* pA10 = pA00 + (size_t)128 * K_;
  const _Float16* pA11 = pA01 + (size_t)128 * K_;
  const _Float16* pB00 = Bt + ((size_t)(nb * 256) + sr) * K_ + cc * 8;
  const _Float16* pB01 = Bt + ((size_t)(nb * 256) + 64 + sr) * K_ + cc * 8;
  const _Float16* pB10 = pB00 + (size_t)128 * K_;
  const _Float16* pB11 = pB01 + (size_t)128 * K_;
  const int ldst0 = tid * 8;
  const int ldst1 = 4096 + tid * 8;

  const int co0 = ((q) ^ (lm & 7)) * 8;
  const int co1 = ((4 + q) ^ (lm & 7)) * 8;
  const int aro = wm * 8192 + lm * 64;
  const int bro = (wn >> 1) * 8192 + ((wn & 1) * 64 + lm) * 64;

  f32x4 acc[8][4];
  #pragma unroll
  for (int i = 0; i < 8; ++i)
    #pragma unroll
    for (int j = 0; j < 4; ++j) acc[i][j] = (f32x4){0.f, 0.f, 0.f, 0.f};

  STG(pA00, pA01, As, 0, 0);
  STG(pA10, pA11, As, 1, 0);
  STG(pB00, pB01, Bs, 0, 0);
  STG(pB10, pB11, Bs, 1, 0);
  asm volatile("s_waitcnt vmcnt(0)" ::: "memory");
  BAR256();

  const int NT = K >> 6;
  for (int kt = 0; kt < NT; ++kt) {
    const int s = kt & 1;
    const int sb = s * 16384;
    const int snb = (s ^ 1) * 2;
    const int kkn = (kt + 1) * 64;
    const bool pf = (kt + 1) < NT;
    half8 af[4][2], bf[2][2];

    #pragma unroll
    for (int j = 0; j < 4; ++j) {
      af[j][0] = *(const half8*)&As[sb + aro + j * 1024 + co0];
      af[j][1] = *(const half8*)&As[sb + aro + j * 1024 + co1];
    }
    #pragma unroll
    for (int n = 0; n < 2; ++n) {
      bf[n][0] = *(const half8*)&Bs[sb + bro + n * 1024 + co0];
      bf[n][1] = *(const half8*)&Bs[sb + bro + n * 1024 + co1];
    }
    if (pf) { STG(pA00, pA01, As, snb, kkn); STG(pA10, pA11, As, snb + 1, kkn); }
    BAR256();
    __builtin_amdgcn_s_setprio(1);
    #pragma unroll
    for (int j = 0; j < 4; ++j)
      #pragma unroll
      for (int n = 0; n < 2; ++n) {
        acc[j][n] = mfma_f16(af[j][0], bf[n][0], acc[j][n]);
        acc[j][n] = mfma_f16(af[j][1], bf[n][1], acc[j][n]);
      }
    __builtin_amdgcn_s_setprio(0);
    BAR256();

    #pragma unroll
    for (int n = 0; n < 2; ++n) {
      bf[n][0] = *(const half8*)&Bs[sb + bro + (2 + n) * 1024 + co0];
      bf[n][1] = *(const half8*)&Bs[sb + bro + (2 + n) * 1024 + co1];
    }
    if (pf) { STG(pB00, pB01, Bs, snb, kkn); STG(pB10, pB11, Bs, snb + 1, kkn); }
    BAR256();
    __builtin_amdgcn_s_setprio(1);
    #pragma unroll
    for (int j = 0; j < 4; ++j)
      #pragma unroll
      for (int n = 0; n < 2; ++n) {
        acc[j][2 + n] = mfma_f16(af[j][0], bf[n][0], acc[j][2 + n]);
        acc[j][2 + n] = mfma_f16(af[j][1], bf[n][1], acc[j][2 + n]);
      }
    __builtin_amdgcn_s_setprio(0);
    BAR256();

    #pragma unroll
    for (int j = 0; j < 4; ++j) {
      af[j][0] = *(const half8*)&As[sb + aro + (4 + j) * 1024 + co0];
      af[j][1] = *(const half8*)&As[sb + aro + (4 + j) * 1024 + co1];
    }
    BAR256();
    __builtin_amdgcn_s_setprio(1);
    #pragma unroll
    for (int j = 0; j < 4; ++j)
      #pragma unroll
      for (int n = 0; n < 2; ++n) {
        acc[4 + j][2 + n] = mfma_f16(af[j][0], bf[n][0], acc[4 + j][2 + n]);
        acc[4 + j][2 + n] = mfma_f16(af[j][1], bf[n][1], acc[4 + j][2 + n]);
      }
    __builtin_amdgcn_s_setprio(0);
    BAR256();

    #pragma unroll
    for (int n = 0; n < 2; ++n) {
      bf[n][0] = *(const half8*)&Bs[sb + bro + n * 1024 + co0];
      bf[n][1] = *(const half8*)&Bs[sb + bro + n * 1024 + co1];
    }
    BAR256();
    __builtin_amdgcn_s_setprio(1);
    #pragma unroll
    for (int j = 0; j < 4; ++j)
      #pragma unroll
      for (int n = 0; n < 2; ++n) {
        acc[4 + j][n] = mfma_f16(af[j][0], bf[n][0], acc[4 + j][n]);
        acc[4 + j][n] = mfma_f16(af[j][1], bf[n][1], acc[4 + j][n]);
      }
    __builtin_amdgcn_s_setprio(0);
    asm volatile("s_waitcnt vmcnt(0)" ::: "memory");
    BAR256();
  }

  constexpr int CS = 264;
  _Float16* Cs = smem;
  const float* bp = bias + nb * 256 + wn * 64 + lm;
  const int crow = tid >> 2, cq = tid & 3;
  #pragma unroll
  for (int h = 0; h < 2; ++h) {
    if (wm == h) {
      #pragma unroll
      for (int ni = 0; ni < 4; ++ni) {
        float bv = bp[ni * 16];
        #pragma unroll
        for (int mi = 0; mi < 8; ++mi)
          #pragma unroll
          for (int rr = 0; rr < 4; ++rr) {
            float v = acc[mi][ni][rr] + bv;
            if (RELU) v = v > 0.f ? v : 0.f;
            Cs[(mi * 16 + q * 4 + rr) * CS + wn * 64 + ni * 16 + lm] =
                (_Float16)v;
          }
      }
    }
    __syncthreads();
    {
      const size_t rbase = (size_t)(mb * 256 + h * 128 + crow) * N + nb * 256;
      #pragma unroll
      for (int j = 0; j < 8; ++j) {
        int c16 = j * 4 + cq;
        *(f32x4*)&C[rbase + c16 * 8] = *(const f32x4*)&Cs[crow * CS + c16 * 8];
      }
    }
    __syncthreads();
  }
}

// ---------------------------------------------------------------------------
// Interaction: per sample, X = [h; emb_rows; zeros] (32x128 fp16), S = X*X^T,
// feat = [h | triu(S[0:27][0:27]) | 0 pad to 512]. One wave per sample.
__global__ __launch_bounds__(256) void interact_kernel(
    const float* __restrict__ x, const float* __restrict__ emb,
    const _Float16* __restrict__ h, _Float16* __restrict__ feat) {
  constexpr int XS = 136;
  __shared__ __align__(16) _Float16 X[4][32 * XS];
  __shared__ __align__(16) _Float16 F[4][512];
  __shared__ int IDX[4][26];
  int tid = threadIdx.x, wv = tid >> 6, lane = tid & 63;
  size_t b = (size_t)blockIdx.x * 4 + wv;

  if (lane < 26) IDX[wv][lane] = ((int)x[b * 39 + 13 + lane]) & VOCAB_MASK;
  {
    const _Float16* hp = h + b * 128;
    *(unsigned*)&X[wv][lane * 2] = *(const unsigned*)&hp[lane * 2];
  }
  #pragma unroll
  for (int r = 27; r < 32; r++) {
    X[wv][r * XS + lane] = (_Float16)0.f;
    X[wv][r * XS + lane + 64] = (_Float16)0.f;
  }
  __syncthreads();

  #pragma unroll
  for (int it = 0; it < 13; it++) {
    int r = 1 + it * 2 + (lane >> 5);
    int c = (lane & 31) * 4;
    int idx = IDX[wv][r - 1];
    float4 v = *(const float4*)(emb + (size_t)idx * 128 + c);
    _Float16* d = &X[wv][r * XS + c];
    d[0] = (_Float16)v.x; d[1] = (_Float16)v.y;
    d[2] = (_Float16)v.z; d[3] = (_Float16)v.w;
  }
  __syncthreads();

  f32x4 zero = {0.f, 0.f, 0.f, 0.f};
  f32x4 acc[2][2] = {{zero, zero}, {zero, zero}};
  int lm = lane & 15, q = lane >> 4;
  #pragma unroll
  for (int ks = 0; ks < 4; ks++) {
    half8 f0 = *(const half8*)&X[wv][(lm) * XS + ks * 32 + q * 8];
    half8 f1 = *(const half8*)&X[wv][(16 + lm) * XS + ks * 32 + q * 8];
    acc[0][0] = mfma_f16(f0, f0, acc[0][0]);
    acc[0][1] = mfma_f16(f0, f1, acc[0][1]);
    acc[1][0] = mfma_f16(f1, f0, acc[1][0]);
    acc[1][1] = mfma_f16(f1, f1, acc[1][1]);
  }

  *(unsigned*)&F[wv][lane * 2] = *(const unsigned*)&X[wv][lane * 2];
  if (lane < 6) F[wv][506 + lane] = (_Float16)0.f;
  #pragma unroll
  for (int mt = 0; mt < 2; mt++)
    #pragma unroll
    for (int nt = 0; nt < 2; nt++)
      #pragma unroll
      for (int r = 0; r < 4; r++) {
        int i = mt * 16 + q * 4 + r;
        int j = nt * 16 + lm;
        if (i <= j && j < 27) {
          int off = 128 + i * 27 - i * (i - 1) / 2 + (j - i);
          F[wv][off] = (_Float16)acc[mt][nt][r];
        }
      }
  __syncthreads();

  *(float4*)(feat + b * 512 + lane * 8) = *(const float4*)&F[wv][lane * 8];
}

// ---------------------------------------------------------------------------
extern "C" void kernel_launch(void* const* d_in, const int* in_sizes, int n_in,
                              void* d_out, int out_size, void* d_ws, size_t ws_size,
                              hipStream_t stream) {
  const float* x   = (const float*)d_in[0];
  const float* emb = (const float*)d_in[1];
  const float* bw0 = (const float*)d_in[2];
  const float* bb0 = (const float*)d_in[3];
  const float* bw1 = (const float*)d_in[4];
  const float* bb1 = (const float*)d_in[5];
  const float* bw2 = (const float*)d_in[6];
  const float* bb2 = (const float*)d_in[7];
  const float* tw0 = (const float*)d_in[8];
  const float* tb0 = (const float*)d_in[9];
  const float* tw1 = (const float*)d_in[10];
  const float* tb1 = (const float*)d_in[11];
  const float* tw2 = (const float*)d_in[12];
  const float* tb2 = (const float*)d_in[13];
  const float* tw3 = (const float*)d_in[14];
  const float* tb3 = (const float*)d_in[15];
  const float* tw4 = (const float*)d_in[16];
  const float* tb4 = (const float*)d_in[17];
  float* out = (float*)d_out;

  char* ws = (char*)d_ws;
  _Float16* w0T = (_Float16*)ws;          // [512][32]
  _Float16* w1T = w0T + 512 * 32;         // [256][512]
  _Float16* w2T = w1T + 256 * 512;        // [128][256]
  _Float16* t0T = w2T + 128 * 256;        // [1024][512]
  _Float16* t1T = t0T + 1024 * 512;       // [1024][1024]
  _Float16* t2T = t1T + 1024 * 1024;      // [512][1024]
  _Float16* t3T = t2T + 512 * 1024;       // [256][512]

  char* P1 = ws + (size_t)(5u << 20);
  char* P2 = ws + (size_t)(37u << 20);
  _Float16* hb = (_Float16*)P2;       // [B][128]
  _Float16* ft = (_Float16*)P1;       // [B][512]
  _Float16* t0 = (_Float16*)P2;       // [B][1024]
  _Float16* t1 = (_Float16*)P1;       // [B][1024]
  _Float16* t2 = (_Float16*)P2;       // [B][512]

  init_fused<<<dim3(32, 32, 8), 256, 0, stream>>>(
      out, bw0, bw1, bw2, tw0, tw1, tw2, tw3,
      w0T, w1T, w2T, t0T, t1T, t2T, t3T);

  bottom_fused<<<256, 512, 0, stream>>>(x, w0T, bb0, w1T, bb1, w2T, bb2, hb);

  interact_kernel<<<BROWS / 4, 256, 0, stream>>>(x, emb, hb, ft);

  gemm256<1><<<256, 512, 0, stream>>>(ft, t0T, tb0, t0, 1024, 512);
  gemm256<1><<<256, 512, 0, stream>>>(t0, t1T, tb1, t1, 1024, 1024);
  gemm256<1><<<128, 512, 0, stream>>>(t1, t2T, tb2, t2, 512, 1024);

  gemm_bt<1, 1><<<128 * 2, 256, 0, stream>>>(t2, t3T, tb3, nullptr,
      BROWS, 256, 512, 2, tw4, tb4, out);
}